// Round 12
// baseline (1356.484 us; speedup 1.0000x reference)
//
#include <hip/hip_runtime.h>
#include <cmath>

// R12: wavefront LSTM. vs R11 (clean A/B, single lever):
//  - FORCE 1 block/CU in the compiler's occupancy model so the register
//    allocator grants >=128 VGPRs: (a) 45KB dynamic LDS (total 85.5KB/block
//    > 80KB = half of 160KB CU pool), (b) __launch_bounds__(896, 4).
//    R7-R11 all got VGPR_Count=64: backend modeled 2 blocks/CU (28 waves ->
//    7/SIMD -> 64-VGPR class) and rematerialized/spilled the 64 weight VGPRs
//    into an L2 reload stream (~229KB/block-step ~= 3-4k cyc/step = the gap
//    between 2k-cyc compute model and 6.2k-cyc measured step).
// Compute structure / maps / handoff: R8-R11 validated, unchanged.

namespace {
constexpr int H = 106, G4 = 424, SEQ = 512, BB = 256, KIN0 = 100;
constexpr int UST = 392;            // su row stride (f16) = 196 dwords
constexpr int GST = 436;            // gates row stride (f32)
constexpr int NTHR = 896;           // 14 waves
constexpr int RGN = 16;             // rowgroups (16 rows each)
constexpr int NLAYER = 11;
constexpr int RD = 16;              // ring depth (steps)
constexpr int REL = 56;             // u64 elements per ring row
constexpr size_t CNT_STRIDE = 16;   // dwords per counter (64B)
constexpr size_t RING_OFF_B = 65536;
constexpr size_t RING_PER_L = (size_t)RD * BB * REL;   // u64 elements
constexpr unsigned DYN_LDS = 45056; // pad: 40448 static + 45056 = 85504 > 81920

using f16x8 = __attribute__((ext_vector_type(8))) _Float16;
using f32x4 = __attribute__((ext_vector_type(4))) float;
typedef unsigned long long u64;

__device__ __forceinline__ u64 ald(const u64* p) {
    return __hip_atomic_load(p, __ATOMIC_RELAXED, __HIP_MEMORY_SCOPE_AGENT);
}
__device__ __forceinline__ void ast(u64* p, u64 v) {
    __hip_atomic_store(p, v, __ATOMIC_RELAXED, __HIP_MEMORY_SCOPE_AGENT);
}
__device__ __forceinline__ void spinc(const unsigned* p, unsigned tgt) {
    while (__hip_atomic_load(p, __ATOMIC_RELAXED, __HIP_MEMORY_SCOPE_AGENT) < tgt)
        __builtin_amdgcn_s_sleep(8);
}
__device__ __forceinline__ float fast_tanh(float x) {
    float t = __expf(2.0f * x);
    return 1.0f - 2.0f / (t + 1.0f);
}
__device__ __forceinline__ float act_gate(float g, bool istanh) {
    float s = istanh ? 2.0f * g : g;
    float r = 1.0f / (1.0f + __expf(-s));
    return istanh ? 2.0f * r - 1.0f : r;
}
__device__ __forceinline__ unsigned packh2(float a, float b) {
    unsigned lo = (unsigned)__builtin_bit_cast(unsigned short, (_Float16)a);
    unsigned hi = (unsigned)__builtin_bit_cast(unsigned short, (_Float16)b);
    return (hi << 16) | lo;
}

__global__ __launch_bounds__(NTHR, 4)
void lstm_wave(const float* __restrict__ noise,   // (512,256,100) f32
               float* __restrict__ yout,          // (512,256,106) f32
               unsigned* cnt, u64* ring,
               const float* __restrict__ W_ih0, const float* __restrict__ W_hh0,
               const float* __restrict__ b_ih0, const float* __restrict__ b_hh0,
               const float* __restrict__ W_ih,  const float* __restrict__ W_hh,
               const float* __restrict__ b_ih,  const float* __restrict__ b_hh)
{
    extern __shared__ char dyn_pad[];   // occupancy clamp; also keeps LDS>80KB
    const int l = blockIdx.x / RGN;
    const int rg = blockIdx.x % RGN;
    const bool LAST = (l == NLAYER - 1);
    const int K_IN = (l == 0) ? KIN0 : H;

    const float* Wih = (l == 0) ? W_ih0 : W_ih + (size_t)(l - 1) * G4 * H;
    const float* Whh = (l == 0) ? W_hh0 : W_hh + (size_t)(l - 1) * G4 * H;
    const float* pbi = (l == 0) ? b_ih0 : b_ih + (size_t)(l - 1) * G4;
    const float* pbh = (l == 0) ? b_hh0 : b_hh + (size_t)(l - 1) * G4;

    unsigned* cons_my = cnt + (size_t)(l * RGN + rg) * CNT_STRIDE;
    unsigned* cons_in = cnt + (size_t)((l - 1) * RGN + rg) * CNT_STRIDE;
    u64* ring_in  = ring + (size_t)(l - 1) * RING_PER_L;
    u64* ring_out = ring + (size_t)l * RING_PER_L;

    // su row: [x_slot0:0..127 | x_slot1:128..255 | h:256..361 | pad..391] f16
    __shared__ __align__(16) _Float16 su[16 * UST];
    __shared__ float gl[16 * GST];
    (void)dyn_pad;

    const int tid = threadIdx.x;
    const int w = tid >> 6, lane = tid & 63;
    const int l16 = lane & 15, kg = lane >> 4;
    const int lm = tid / 56, ld = tid % 56;   // loader map (row, element)

    // ---- weights: 2 N-tiles/wave, 8 k-steps (validated R8-R11) ----
    f16x8 bf[2][8];
    float bias[2];
    #pragma unroll
    for (int t = 0; t < 2; ++t) {
        const int n = 16 * (2 * w + t) + l16;
        const bool valid = n < G4;
        const float* pwx = Wih + (size_t)(valid ? n : 0) * K_IN;
        const float* pwh = Whh + (size_t)(valid ? n : 0) * H;
        #pragma unroll
        for (int q = 0; q < 8; ++q) {
            f16x8 v;
            #pragma unroll
            for (int e = 0; e < 8; ++e) {
                const int k = 32 * q + 8 * kg + e;
                float f = 0.0f;
                if (valid) {
                    if (k < 128) { if (k < K_IN) f = pwx[k]; }
                    else { const int kh = k - 128; if (kh < H) f = pwh[kh]; }
                }
                v[e] = (_Float16)f;
            }
            bf[t][q] = v;
        }
        bias[t] = valid ? (pbi[n] + pbh[n]) : 0.0f;
    }

    // ---- init: zero su, fetch x_0 into x slot 0 (tag 1) ----
    for (int i = tid; i < 16 * (UST / 2); i += NTHR) ((unsigned*)su)[i] = 0;
    float c0 = 0.0f, c1 = 0.0f;
    __syncthreads();
    {
        unsigned xr = 0;
        if (l == 0) {
            if (ld < 50) {
                const float2 v = *(const float2*)(noise + ((size_t)rg * 16 + lm) * KIN0 + 2 * ld);
                xr = packh2(v.x, v.y);
            }
        } else {
            const u64* p = ring_in + ((size_t)0 * BB + rg * 16 + lm) * REL + ld;
            u64 v = ald(p);
            while ((unsigned)(v >> 32) != 1u) { __builtin_amdgcn_s_sleep(1); v = ald(p); }
            xr = (unsigned)v;
        }
        ((unsigned*)su)[lm * 196 + ld] = xr;
    }
    __syncthreads();

    const int um = tid / 53, up = tid % 53;   // update map (row, H-pair)
    const _Float16* arow = su + (size_t)l16 * UST;

    // ---- prelude: accx for s=0 (x slot 0); issue ring load for x_1 ----
    f32x4 accx[2] = {{0, 0, 0, 0}, {0, 0, 0, 0}};
    {
        const _Float16* ax = arow + 8 * kg;
        #pragma unroll
        for (int q = 0; q < 4; ++q) {
            const f16x8 a = *(const f16x8*)(ax + 32 * q);
            accx[0] = __builtin_amdgcn_mfma_f32_16x16x32_f16(a, bf[0][q], accx[0], 0, 0, 0);
            accx[1] = __builtin_amdgcn_mfma_f32_16x16x32_f16(a, bf[1][q], accx[1], 0, 0, 0);
        }
    }
    u64 vprev = 0;   // in-flight ring word for x_{s+1}
    if (l > 0) vprev = ald(ring_in + ((size_t)(1 % RD) * BB + rg * 16 + lm) * REL + ld);

    for (int s = 0; s < SEQ; ++s) {
        // phase a: issue ring load for x_{s+2}; l==0 loads noise for x_{s+1}
        u64 vnext = 0; unsigned xr = 0;
        const bool wantx = (s + 1 < SEQ);
        if (l > 0) {
            if (s + 2 < SEQ)
                vnext = ald(ring_in + ((size_t)((s + 2) % RD) * BB + rg * 16 + lm) * REL + ld);
        } else if (wantx && ld < 50) {
            const float2 t = *(const float2*)(noise + ((size_t)(s + 1) * BB + rg * 16 + lm) * KIN0 + 2 * ld);
            xr = packh2(t.x, t.y);
        }
        // backpressure, batched 1/8 steps
        if (tid == 0 && !LAST && s >= RD && (s & 7) == 0)
            spinc(cons_my, (unsigned)(s - 8));

        // phase e: h-part MFMAs (C init = accx from previous step's phase i)
        f32x4 acc[2] = {accx[0], accx[1]};
        const _Float16* ah = arow + 256 + 8 * kg;
        #pragma unroll
        for (int q = 4; q < 8; ++q) {
            const f16x8 a = *(const f16x8*)(ah + 32 * (q - 4));
            acc[0] = __builtin_amdgcn_mfma_f32_16x16x32_f16(a, bf[0][q], acc[0], 0, 0, 0);
            acc[1] = __builtin_amdgcn_mfma_f32_16x16x32_f16(a, bf[1][q], acc[1], 0, 0, 0);
        }
        // phase f: activation + gates to LDS. C map: row=4*kg+r, col=l16.
        #pragma unroll
        for (int t = 0; t < 2; ++t) {
            const int n = 16 * (2 * w + t) + l16;
            if (n < G4) {
                const bool istanh = (n >= 2 * H) && (n < 3 * H);
                #pragma unroll
                for (int r = 0; r < 4; ++r)
                    gl[(4 * kg + r) * GST + n] = act_gate(acc[t][r] + bias[t], istanh);
            }
        }
        // phase d: verify tag of x_{s+1} + install into slot (s+1)&1
        if (wantx) {
            if (l > 0) {
                const unsigned expt = (unsigned)(s + 2);
                const u64* pin = ring_in + ((size_t)((s + 1) % RD) * BB + rg * 16 + lm) * REL + ld;
                while ((unsigned)(vprev >> 32) != expt) { __builtin_amdgcn_s_sleep(1); vprev = ald(pin); }
                xr = (unsigned)vprev;
            }
            ((unsigned*)su)[lm * 196 + ((s + 1) & 1) * 64 + ld] = xr;
        }
        vprev = vnext;
        __syncthreads();   // barrier G: gates + x_{s+1} install + h reads done

        // phase h: state update + publish
        if (tid < 848) {
            const float* gm = gl + um * GST;
            const float2 vi = *(const float2*)(gm + 2 * up);
            const float2 vf = *(const float2*)(gm + H + 2 * up);
            const float2 vg = *(const float2*)(gm + 2 * H + 2 * up);
            const float2 vo = *(const float2*)(gm + 3 * H + 2 * up);
            c0 = fmaf(vf.x, c0, vi.x * vg.x);
            c1 = fmaf(vf.y, c1, vi.y * vg.y);
            const float h0 = vo.x * fast_tanh(c0);
            const float h1 = vo.y * fast_tanh(c1);
            const unsigned hw = packh2(h0, h1);
            ((unsigned*)su)[um * 196 + 128 + up] = hw;
            if (LAST) {
                *(float2*)(yout + ((size_t)s * BB + rg * 16 + um) * H + 2 * up) =
                    make_float2(h0, h1);
            } else {
                ast(ring_out + ((size_t)(s % RD) * BB + rg * 16 + um) * REL + up,
                    ((u64)(unsigned)(s + 1) << 32) | hw);
            }
        } else if (!LAST) {   // pad elements 53..55 = 0, tagged
            const int t2 = tid - 848, m = t2 / 3, dd = t2 % 3;
            ast(ring_out + ((size_t)(s % RD) * BB + rg * 16 + m) * REL + 53 + dd,
                (u64)(unsigned)(s + 1) << 32);
        }
        // phase i: x-part MFMAs for step s+1 (off the h critical chain)
        if (wantx) {
            const _Float16* ax = arow + ((s + 1) & 1) * 128 + 8 * kg;
            accx[0] = f32x4{0, 0, 0, 0};
            accx[1] = f32x4{0, 0, 0, 0};
            #pragma unroll
            for (int q = 0; q < 4; ++q) {
                const f16x8 a = *(const f16x8*)(ax + 32 * q);
                accx[0] = __builtin_amdgcn_mfma_f32_16x16x32_f16(a, bf[0][q], accx[0], 0, 0, 0);
                accx[1] = __builtin_amdgcn_mfma_f32_16x16x32_f16(a, bf[1][q], accx[1], 0, 0, 0);
            }
        }
        __syncthreads();   // barrier U: h_s + ring writes + accx complete

        if (tid == 0 && l > 0 && s + 1 < SEQ)
            __hip_atomic_store(cons_in, (unsigned)(s + 2),
                               __ATOMIC_RELAXED, __HIP_MEMORY_SCOPE_AGENT);
    }
}
}  // namespace

extern "C" void kernel_launch(void* const* d_in, const int* in_sizes, int n_in,
                              void* d_out, int out_size, void* d_ws, size_t ws_size,
                              hipStream_t stream) {
    const float* noise = (const float*)d_in[0];
    const float* W_ih0 = (const float*)d_in[1];
    const float* W_hh0 = (const float*)d_in[2];
    const float* b_ih0 = (const float*)d_in[3];
    const float* b_hh0 = (const float*)d_in[4];
    const float* W_ih  = (const float*)d_in[5];
    const float* W_hh  = (const float*)d_in[6];
    const float* b_ih  = (const float*)d_in[7];
    const float* b_hh  = (const float*)d_in[8];

    // clear counters + rings each call (replay-safe)
    const size_t clear_bytes = RING_OFF_B + (size_t)NLAYER * RING_PER_L * sizeof(u64);
    hipMemsetAsync(d_ws, 0, clear_bytes, stream);

    unsigned* cnt = (unsigned*)d_ws;
    u64* ring = (u64*)((char*)d_ws + RING_OFF_B);

    lstm_wave<<<dim3(NLAYER * RGN), dim3(NTHR), DYN_LDS, stream>>>(
        noise, (float*)d_out, cnt, ring,
        W_ih0, W_hh0, b_ih0, b_hh0, W_ih, W_hh, b_ih, b_hh);
}